// Round 7
// baseline (558.288 us; speedup 1.0000x reference)
//
#include <hip/hip_runtime.h>
#include <hip/hip_fp16.h>

// Problem: B=32, S=2048, D=1024, H=1024
//   qp = query@W2 [B,H]; keys = values@W1 [B,S,H]; scores = tanh(qp+keys)@v [B,S]
//   w = softmax(scores); ctx = w@values [B,D]. Outputs: ctx (32768) ++ w (65536).
//
// R10: k_scores software-pipelined with counted lgkmcnt. R9 post-mortem: the
// per-phase {reads; barrier; lgkm(0); MFMA} structure serializes LDS-drain
// and MFMA (ledger: 2304 + 2483 + overhead = 6900 cyc/step, 32% MfmaUtil).
// Fix: issue phase p+1's ds_reads in phase p, wait lgkmcnt(N)=just-issued
// count (retires only p's reads), double-buffered fragment regs. One
// barrier/K-step at end-P2 (vmcnt(0)+lgkm(0), ~2 phases of slack for the
// gl_lds prefetch); P3 pre-reads next tile's first fragments post-barrier.

typedef _Float16 v8h  __attribute__((ext_vector_type(8)));
typedef float    v4f  __attribute__((ext_vector_type(4)));

#define B_DIM 32
#define S_DIM 2048
#define D_DIM 1024
#define H_DIM 1024

// workspace layout (bytes) -- ~130.5 MiB
#define WS_V16    0u                       // [B][S][D] fp16 = 128 MiB
#define WS_W1T    134217728u               // [H][D] fp16 = 2 MiB
#define WS_QP     (WS_W1T + 2097152u)      // [B][H] fp32
#define WS_SCORES (WS_QP + 131072u)        // [B][S] fp32 (atomicAdd target)

// async global->LDS, 16B per lane; LDS dest = wave-uniform base + lane*16
__device__ __forceinline__ void gl_lds16(const _Float16* g, _Float16* l) {
    __builtin_amdgcn_global_load_lds(
        (const __attribute__((address_space(1))) void*)g,
        (__attribute__((address_space(3))) void*)l, 16, 0, 0);
}

// ---------------- K0: prep ----------------
// blocks [0,256):     qp = query @ W2  (32 b x 8 hc, 2-way K-split per block)
// blocks [256,512):   W1 [D,H] -> W1T [H,D] fp16
// blocks [512,544):   zero scores
// blocks [544,33312): values fp32 -> fp16 (nontemporal reads)
__global__ void k_prep(const float* __restrict__ values, _Float16* __restrict__ v16,
                       const float* __restrict__ W1, _Float16* __restrict__ w1t,
                       const float* __restrict__ query, const float* __restrict__ W2,
                       float* __restrict__ qp, float* __restrict__ scores) {
    __shared__ float smem[64 * 65];
    int bid = blockIdx.x, tid = threadIdx.x;
    if (bid >= 544) {
        size_t i = ((size_t)(bid - 544) * 256 + tid) * 8;
        v4f f0 = __builtin_nontemporal_load((const v4f*)(values + i));
        v4f f1 = __builtin_nontemporal_load((const v4f*)(values + i + 4));
        v8h hv;
        hv[0] = (_Float16)f0[0]; hv[1] = (_Float16)f0[1];
        hv[2] = (_Float16)f0[2]; hv[3] = (_Float16)f0[3];
        hv[4] = (_Float16)f1[0]; hv[5] = (_Float16)f1[1];
        hv[6] = (_Float16)f1[2]; hv[7] = (_Float16)f1[3];
        *(v8h*)(v16 + i) = hv;
    } else if (bid < 256) {
        int b = bid >> 3, hc = bid & 7;
        #pragma unroll
        for (int i = 0; i < 4; ++i)
            smem[i * 256 + tid] = query[b * D_DIM + i * 256 + tid];
        __syncthreads();
        int hh = tid & 127, half = tid >> 7;
        int h = hc * 128 + hh;
        const float* w2p = W2 + (size_t)(half * 512) * H_DIM + h;
        float acc = 0.f;
        #pragma unroll 8
        for (int d = 0; d < 512; ++d)
            acc += smem[half * 512 + d] * w2p[(size_t)d * H_DIM];
        smem[1024 + tid] = acc;
        __syncthreads();
        if (tid < 128)
            qp[b * H_DIM + hc * 128 + tid] = smem[1024 + tid] + smem[1024 + 128 + tid];
    } else if (bid < 512) {
        int j = bid - 256;
        int h0 = (j & 15) * 64, d0 = (j >> 4) * 64;
        #pragma unroll
        for (int i = 0; i < 16; ++i) {
            int idx = i * 256 + tid;
            int dd = idx >> 6, hh = idx & 63;
            smem[dd * 65 + hh] = W1[(size_t)(d0 + dd) * H_DIM + h0 + hh];
        }
        __syncthreads();
        #pragma unroll
        for (int i = 0; i < 16; ++i) {
            int idx = i * 256 + tid;
            int hh = idx >> 6, dd = idx & 63;
            w1t[(size_t)(h0 + hh) * D_DIM + d0 + dd] = (_Float16)smem[dd * 65 + hh];
        }
    } else {
        int j = bid - 512;
        size_t o = (size_t)j * 2048 + tid * 8;
        *(v4f*)(scores + o)     = (v4f){0.f, 0.f, 0.f, 0.f};
        *(v4f*)(scores + o + 4) = (v4f){0.f, 0.f, 0.f, 0.f};
    }
}

// ---------------- K1: fused scores GEMM (counted-lgkm pipeline) -------------
// grid = 1024 blocks (XCD-chunk swizzled), 512 thr (2m x 4n waves)
// block tile 256(m) x 256(n), wave tile 128x64, BK=64, 16 K-steps.
// 4 phases/step: P0 af_a*bf_a, P1 af_b*bf_a, P2 af_a*bf_b, P3 af_b*bf_b;
// each phase issues the NEXT phase's ds_reads first, then waits a counted
// lgkmcnt for its own operands -> LDS drain overlaps MFMA.

#define SB __builtin_amdgcn_sched_barrier(0)

#define READ_AF(dst, CA, mh, kk)                                           \
    _Pragma("unroll")                                                      \
    for (int i_ = 0; i_ < 4; ++i_) {                                       \
        int row_ = wm * 128 + (mh) * 64 + i_ * 16 + l15;                   \
        int ph_  = ((kk) * 4 + quad) ^ (row_ & 7);                         \
        dst[i_] = *(const v8h*)(&(CA)[row_ * 64 + ph_ * 8]);               \
    }

#define READ_BF(dst, CB, kk)                                               \
    _Pragma("unroll")                                                      \
    for (int j_ = 0; j_ < 4; ++j_) {                                       \
        int row_ = wn * 64 + j_ * 16 + l15;                                \
        int ph_  = ((kk) * 4 + quad) ^ (row_ & 7);                         \
        dst[j_] = *(const v8h*)(&(CB)[row_ * 64 + ph_ * 8]);               \
    }

#define MFMA16(af, bf, mh)                                                 \
    __builtin_amdgcn_s_setprio(1);                                         \
    _Pragma("unroll")                                                      \
    for (int i_ = 0; i_ < 4; ++i_)                                         \
        _Pragma("unroll")                                                  \
        for (int j_ = 0; j_ < 4; ++j_)                                     \
            acc[(mh) * 4 + i_][j_] = __builtin_amdgcn_mfma_f32_16x16x32_f16( \
                af[i_], bf[j_], acc[(mh) * 4 + i_][j_], 0, 0, 0);          \
    __builtin_amdgcn_s_setprio(0);

#define STAGE(dstbuf, src, koff)                                           \
    _Pragma("unroll")                                                      \
    for (int i_ = 0; i_ < 4; ++i_) {                                       \
        int brow_ = i_ * 64 + wid * 8;                                     \
        int row_  = brow_ + srow;                                          \
        int kgs_  = kg ^ (row_ & 7);                                       \
        gl_lds16((src) + (size_t)row_ * D_DIM + (koff) + kgs_ * 8,         \
                 &(dstbuf)[brow_ * 64]);                                   \
    }

__global__ __launch_bounds__(512, 2) void k_scores(
        const _Float16* __restrict__ v16, const _Float16* __restrict__ w1t,
        const float* __restrict__ qp, const float* __restrict__ v,
        float* __restrict__ scores) {
    __shared__ _Float16 As[2][256 * 64];   // 2 x 32 KiB (buf0 reused in epilogue)
    __shared__ _Float16 Bs[2][256 * 64];   // 2 x 32 KiB

    int tid = threadIdx.x;
    int wid = tid >> 6, lane = tid & 63;
    int quad = lane >> 4, l15 = lane & 15;
    int wm = wid >> 2, wn = wid & 3;     // 2 x 4 wave grid

    // XCD-chunked bijective swizzle (1024 % 8 == 0)
    int bid = blockIdx.x;
    int idx = (bid & 7) * 128 + (bid >> 3);
    int np  = idx & 3;
    int mtb = idx >> 2;          // 0..255
    int b   = mtb >> 3;          // 0..31
    int m0  = (mtb & 7) * 256;
    int n0  = np * 256;

    int srow = lane >> 3;
    int kg   = lane & 7;
    const _Float16* a16 = v16 + ((size_t)b * S_DIM + m0) * D_DIM;
    const _Float16* bw  = w1t + (size_t)n0 * D_DIM;

    v4f acc[8][4];
    #pragma unroll
    for (int i = 0; i < 8; ++i)
        #pragma unroll
        for (int j = 0; j < 4; ++j) acc[i][j] = (v4f){0.f, 0.f, 0.f, 0.f};

    v8h af_a[4], af_b[4], bf_a[4], bf_b[4];

    // ---- prologue: stage tile 0; preload P0 fragments ----
    STAGE(As[0], a16, 0);
    STAGE(Bs[0], bw, 0);
    asm volatile("s_waitcnt vmcnt(0)" ::: "memory");
    __builtin_amdgcn_s_barrier();
    READ_AF(af_a, As[0], 0, 0);
    READ_BF(bf_a, Bs[0], 0);
    // outstanding: 8 ds_reads (= steady-state entry condition)

    #pragma unroll 1
    for (int t = 0; t < 16; ++t) {
        const _Float16* cA = As[t & 1];
        const _Float16* cB = Bs[t & 1];
        _Float16* nA = As[(t + 1) & 1];
        _Float16* nB = Bs[(t + 1) & 1];
        int k1 = ((t + 1) & 15) * 64;
        bool pf = (t < 15);

        // ---- P0: MFMA af_a*bf_a (mh0,kk0); issue af_b<-(mh1,kk0), A-prefetch
        if (pf) STAGE(nA, a16, k1);
        READ_AF(af_b, cA, 1, 0);
        SB; asm volatile("s_waitcnt lgkmcnt(4)" ::: "memory"); SB;
        MFMA16(af_a, bf_a, 0); SB;

        // ---- P1: MFMA af_b*bf_a (mh1,kk0); issue af_a<-(mh0,kk1), bf_b<-(kk1), B-prefetch
        if (pf) STAGE(nB, bw, k1);
        READ_AF(af_a, cA, 0, 1);
        READ_BF(bf_b, cB, 1);
        SB; asm volatile("s_waitcnt lgkmcnt(8)" ::: "memory"); SB;
        MFMA16(af_b, bf_a, 1); SB;

        // ---- P2: MFMA af_a*bf_b (mh0,kk1); issue af_b<-(mh1,kk1)
        READ_AF(af_b, cA, 1, 1);
        SB; asm volatile("s_waitcnt lgkmcnt(4)" ::: "memory"); SB;
        MFMA16(af_a, bf_b, 0); SB;

        // buffer-swap point: prefetch landed (2 phases slack), all reads done
        asm volatile("s_waitcnt vmcnt(0) lgkmcnt(0)" ::: "memory");
        __builtin_amdgcn_s_barrier();

        // ---- P3: MFMA af_b*bf_b (mh1,kk1); pre-read next tile's P0 frags
        if (pf) {
            READ_AF(af_a, nA, 0, 0);
            READ_BF(bf_a, nB, 0);
        }
        SB;
        MFMA16(af_b, bf_b, 1); SB;
    }

    // ---- epilogue: scores = tanh(acc + qp) . v, reduced over n ----
    float qpv[4], vv[4];
    #pragma unroll
    for (int nt = 0; nt < 4; ++nt) {
        int ng = n0 + wn * 64 + nt * 16 + l15;
        qpv[nt] = qp[b * H_DIM + ng];
        vv[nt]  = v[ng];
    }

    float* s_scores = (float*)&As[0][0];   // all LDS reads done (last barrier)
    if (tid < 256) s_scores[tid] = 0.f;
    __syncthreads();

    #pragma unroll
    for (int mt = 0; mt < 8; ++mt) {
        #pragma unroll
        for (int r = 0; r < 4; ++r) {
            float s = 0.f;
            #pragma unroll
            for (int nt = 0; nt < 4; ++nt) {
                float x = acc[mt][nt][r] + qpv[nt];
                float e = __expf(2.f * x);           // tanh(x) = 1 - 2/(e^{2x}+1)
                s += (1.f - 2.f / (e + 1.f)) * vv[nt];
            }
            s += __shfl_xor(s, 1);
            s += __shfl_xor(s, 2);
            s += __shfl_xor(s, 4);
            s += __shfl_xor(s, 8);
            if (l15 == 0)
                atomicAdd(&s_scores[wm * 128 + mt * 16 + quad * 4 + r], s);
        }
    }
    __syncthreads();
    if (tid < 256) atomicAdd(&scores[(size_t)b * S_DIM + m0 + tid], s_scores[tid]);
}

// ---------------- K2: fused softmax + context ----------------
// One block per batch row b (32 blocks x 1024 thr). Softmax exact (full wout);
// ctx over only weights > 1e-7 (winner-take-all; skipped mass <= 2048e-7 ->
// |ctx err| ~1e-3 << 8.2e-2 threshold). Reads values fp32 directly.
__global__ __launch_bounds__(1024) void k_finish(
        const float* __restrict__ scores, const float* __restrict__ values,
        float* __restrict__ wout, float* __restrict__ ctx) {
    __shared__ float s_w[2048];
    __shared__ int   s_idx[2048];
    __shared__ float red[16];
    __shared__ float s_bcast;
    __shared__ int   s_cnt;

    int b = blockIdx.x, tid = threadIdx.x;
    int lane = tid & 63, wid = tid >> 6;

    float s0 = scores[b * S_DIM + tid];
    float s1 = scores[b * S_DIM + 1024 + tid];

    float m = fmaxf(s0, s1);
    #pragma unroll
    for (int off = 1; off <= 32; off <<= 1) m = fmaxf(m, __shfl_xor(m, off));
    if (lane == 0) red[wid] = m;
    if (tid == 0) s_cnt = 0;
    __syncthreads();
    if (tid == 0) {
        float mm = red[0];
        #pragma unroll
        for (int i = 1; i < 16; ++i) mm = fmaxf(mm, red[i]);
        s_bcast = mm;
    }
    __syncthreads();
    float rowmax = s_bcast;

    float e0 = __expf(s0 - rowmax);
    float e1 = __expf(s1 - rowmax);
    float sum = e0 + e1;
    #pragma unroll
    for (int off = 1; off <= 32; off <<= 1) sum += __shfl_xor(sum, off);
    if (lane == 0) red[wid] = sum;
    __syncthreads();
    if (tid == 0) {
        float ss = red[0];
        #pragma unroll
        for (int i = 1; i < 16; ++i) ss += red[i];
        s_bcast = 1.f / ss;
    }
    __syncthreads();
    float inv = s_bcast;

    float w0 = e0 * inv, w1 = e1 * inv;
    wout[b * S_DIM + tid]        = w0;
    wout[b * S_DIM + 1024 + tid] = w1;
    s_w[tid]        = w0;
    s_w[tid + 1024] = w1;

    if (w0 > 1e-7f) { int p = atomicAdd(&s_cnt, 1); s_idx[p] = tid; }
    if (w1 > 1e-7f) { int p = atomicAdd(&s_cnt, 1); s_idx[p] = tid + 1024; }
    __syncthreads();
    int cnt = s_cnt;

    float acc = 0.f;
    const float* vb = values + (size_t)b * S_DIM * D_DIM + tid;
    for (int i = 0; i < cnt; ++i) {
        int s = s_idx[i];
        acc += s_w[s] * vb[(size_t)s * D_DIM];
    }
    ctx[b * D_DIM + tid] = acc;
}

extern "C" void kernel_launch(void* const* d_in, const int* in_sizes, int n_in,
                              void* d_out, int out_size, void* d_ws, size_t ws_size,
                              hipStream_t stream) {
    const float* query  = (const float*)d_in[0];
    const float* values = (const float*)d_in[1];
    const float* W1     = (const float*)d_in[2];
    const float* W2     = (const float*)d_in[3];
    const float* v      = (const float*)d_in[4];

    char* ws = (char*)d_ws;
    _Float16* v16 = (_Float16*)(ws + WS_V16);
    _Float16* w1t = (_Float16*)(ws + WS_W1T);
    float* qp     = (float*)(ws + WS_QP);
    float* scores = (float*)(ws + WS_SCORES);

    float* ctx  = (float*)d_out;            // [32, 1024]
    float* wout = (float*)d_out + 32768;    // [32, 2048]

    k_prep<<<dim3(33312), 256, 0, stream>>>(values, v16, W1, w1t, query, W2, qp, scores);
    k_scores<<<dim3(1024), 512, 0, stream>>>(v16, w1t, qp, v, scores);
    k_finish<<<dim3(32), 1024, 0, stream>>>(scores, values, wout, ctx);
}

// Round 8
// 542.705 us; speedup vs baseline: 1.0287x; 1.0287x over previous
//
#include <hip/hip_runtime.h>
#include <hip/hip_fp16.h>

// Problem: B=32, S=2048, D=1024, H=1024
//   qp = query@W2 [B,H]; keys = values@W1 [B,S,H]; scores = tanh(qp+keys)@v [B,S]
//   w = softmax(scores); ctx = w@values [B,D]. Outputs: ctx (32768) ++ w (65536).
//
// R11: address strength-reduction in k_scores. R10 post-mortem: VALUBusy 37%
// >= MfmaUtil 33% -- ~160 VALU/wave/step recomputing loop-invariant LDS/global
// addresses steals issue slots from MFMA (1 instr/cyc/wave, 2 waves/SIMD).
// Fix: 4 precomputed LDS read bases (kk0/kk1 x A/B; buffer & fragment offsets
// are compile-time immediates folded into ds_read offset:), 2 staging dest
// bases, 8 running global pointers (+64 halves/step). K-loop unrolled x2 so
// the buffer index is a literal. Schedule identical to R10 (counted lgkm).

typedef _Float16 v8h  __attribute__((ext_vector_type(8)));
typedef float    v4f  __attribute__((ext_vector_type(4)));

#define B_DIM 32
#define S_DIM 2048
#define D_DIM 1024
#define H_DIM 1024

// workspace layout (bytes) -- ~130.5 MiB
#define WS_V16    0u                       // [B][S][D] fp16 = 128 MiB
#define WS_W1T    134217728u               // [H][D] fp16 = 2 MiB
#define WS_QP     (WS_W1T + 2097152u)      // [B][H] fp32
#define WS_SCORES (WS_QP + 131072u)        // [B][S] fp32 (atomicAdd target)

// async global->LDS, 16B per lane; LDS dest = wave-uniform base + lane*16
__device__ __forceinline__ void gl_lds16(const _Float16* g, _Float16* l) {
    __builtin_amdgcn_global_load_lds(
        (const __attribute__((address_space(1))) void*)g,
        (__attribute__((address_space(3))) void*)l, 16, 0, 0);
}

// ---------------- K0: prep ----------------
// blocks [0,256):     qp = query @ W2  (32 b x 8 hc, 2-way K-split per block)
// blocks [256,512):   W1 [D,H] -> W1T [H,D] fp16
// blocks [512,544):   zero scores
// blocks [544,33312): values fp32 -> fp16 (nontemporal reads)
__global__ void k_prep(const float* __restrict__ values, _Float16* __restrict__ v16,
                       const float* __restrict__ W1, _Float16* __restrict__ w1t,
                       const float* __restrict__ query, const float* __restrict__ W2,
                       float* __restrict__ qp, float* __restrict__ scores) {
    __shared__ float smem[64 * 65];
    int bid = blockIdx.x, tid = threadIdx.x;
    if (bid >= 544) {
        size_t i = ((size_t)(bid - 544) * 256 + tid) * 8;
        v4f f0 = __builtin_nontemporal_load((const v4f*)(values + i));
        v4f f1 = __builtin_nontemporal_load((const v4f*)(values + i + 4));
        v8h hv;
        hv[0] = (_Float16)f0[0]; hv[1] = (_Float16)f0[1];
        hv[2] = (_Float16)f0[2]; hv[3] = (_Float16)f0[3];
        hv[4] = (_Float16)f1[0]; hv[5] = (_Float16)f1[1];
        hv[6] = (_Float16)f1[2]; hv[7] = (_Float16)f1[3];
        *(v8h*)(v16 + i) = hv;
    } else if (bid < 256) {
        int b = bid >> 3, hc = bid & 7;
        #pragma unroll
        for (int i = 0; i < 4; ++i)
            smem[i * 256 + tid] = query[b * D_DIM + i * 256 + tid];
        __syncthreads();
        int hh = tid & 127, half = tid >> 7;
        int h = hc * 128 + hh;
        const float* w2p = W2 + (size_t)(half * 512) * H_DIM + h;
        float acc = 0.f;
        #pragma unroll 8
        for (int d = 0; d < 512; ++d)
            acc += smem[half * 512 + d] * w2p[(size_t)d * H_DIM];
        smem[1024 + tid] = acc;
        __syncthreads();
        if (tid < 128)
            qp[b * H_DIM + hc * 128 + tid] = smem[1024 + tid] + smem[1024 + 128 + tid];
    } else if (bid < 512) {
        int j = bid - 256;
        int h0 = (j & 15) * 64, d0 = (j >> 4) * 64;
        #pragma unroll
        for (int i = 0; i < 16; ++i) {
            int idx = i * 256 + tid;
            int dd = idx >> 6, hh = idx & 63;
            smem[dd * 65 + hh] = W1[(size_t)(d0 + dd) * H_DIM + h0 + hh];
        }
        __syncthreads();
        #pragma unroll
        for (int i = 0; i < 16; ++i) {
            int idx = i * 256 + tid;
            int hh = idx >> 6, dd = idx & 63;
            w1t[(size_t)(h0 + hh) * D_DIM + d0 + dd] = (_Float16)smem[dd * 65 + hh];
        }
    } else {
        int j = bid - 512;
        size_t o = (size_t)j * 2048 + tid * 8;
        *(v4f*)(scores + o)     = (v4f){0.f, 0.f, 0.f, 0.f};
        *(v4f*)(scores + o + 4) = (v4f){0.f, 0.f, 0.f, 0.f};
    }
}

// ---------------- K1: fused scores GEMM (counted-lgkm, const-addr) ----------
// grid = 1024 blocks (XCD-chunk swizzled), 512 thr (2m x 4n waves)
// block tile 256(m) x 256(n), wave tile 128x64, BK=64, 16 K-steps.
// All LDS fragment reads: precomputed base + compile-time immediate offset.

#define SB __builtin_amdgcn_sched_barrier(0)

#define READ4(dst, base, OFFC)                                              \
    dst[0] = *(const v8h*)((base) + (OFFC));                                \
    dst[1] = *(const v8h*)((base) + (OFFC) + 1024);                         \
    dst[2] = *(const v8h*)((base) + (OFFC) + 2048);                         \
    dst[3] = *(const v8h*)((base) + (OFFC) + 3072);

#define MFMA16(af, bf, mh)                                                  \
    __builtin_amdgcn_s_setprio(1);                                          \
    _Pragma("unroll")                                                       \
    for (int i_ = 0; i_ < 4; ++i_)                                          \
        _Pragma("unroll")                                                   \
        for (int j_ = 0; j_ < 4; ++j_)                                      \
            acc[(mh) * 4 + i_][j_] = __builtin_amdgcn_mfma_f32_16x16x32_f16( \
                af[i_], bf[j_], acc[(mh) * 4 + i_][j_], 0, 0, 0);           \
    __builtin_amdgcn_s_setprio(0);

// issue 4 gl_lds from running pointers; advance pointers by one K-step (64 h)
#define STAGE4(g0, g1, g2, g3, dst, OFFC)                                   \
    gl_lds16(g0, (dst) + (OFFC));                                           \
    gl_lds16(g1, (dst) + (OFFC) + 4096);                                    \
    gl_lds16(g2, (dst) + (OFFC) + 8192);                                    \
    gl_lds16(g3, (dst) + (OFFC) + 12288);                                   \
    g0 += 64; g1 += 64; g2 += 64; g3 += 64;

// one K-step: compute buf BUFC, stage tile->buf BUFC^1, pre-read next frags
#define KSTEP(BUFC, PFC)                                                    \
    {                                                                       \
        if (PFC) { STAGE4(gA0, gA1, gA2, gA3, dA, ((BUFC) ^ 1) * 16384) }   \
        READ4(af_b, rA0, (BUFC) * 16384 + 4096)                             \
        SB; asm volatile("s_waitcnt lgkmcnt(4)" ::: "memory"); SB;          \
        MFMA16(af_a, bf_a, 0); SB;                                          \
        if (PFC) { STAGE4(gB0, gB1, gB2, gB3, dB, ((BUFC) ^ 1) * 16384) }   \
        READ4(af_a, rA1, (BUFC) * 16384)                                    \
        READ4(bf_b, rB1, (BUFC) * 16384)                                    \
        SB; asm volatile("s_waitcnt lgkmcnt(8)" ::: "memory"); SB;          \
        MFMA16(af_b, bf_a, 1); SB;                                          \
        READ4(af_b, rA1, (BUFC) * 16384 + 4096)                             \
        SB; asm volatile("s_waitcnt lgkmcnt(4)" ::: "memory"); SB;          \
        MFMA16(af_a, bf_b, 0); SB;                                          \
        asm volatile("s_waitcnt vmcnt(0) lgkmcnt(0)" ::: "memory");         \
        __builtin_amdgcn_s_barrier();                                       \
        if (PFC) {                                                          \
            READ4(af_a, rA0, ((BUFC) ^ 1) * 16384)                          \
            READ4(bf_a, rB0, ((BUFC) ^ 1) * 16384)                          \
        }                                                                   \
        SB;                                                                 \
        MFMA16(af_b, bf_b, 1); SB;                                          \
    }

__global__ __launch_bounds__(512, 2) void k_scores(
        const _Float16* __restrict__ v16, const _Float16* __restrict__ w1t,
        const float* __restrict__ qp, const float* __restrict__ v,
        float* __restrict__ scores) {
    __shared__ _Float16 As[2][256 * 64];   // 2 x 32 KiB (buf0 reused in epilogue)
    __shared__ _Float16 Bs[2][256 * 64];   // 2 x 32 KiB

    int tid = threadIdx.x;
    int wid = tid >> 6, lane = tid & 63;
    int quad = lane >> 4, l15 = lane & 15;
    int wm = wid >> 2, wn = wid & 3;     // 2 x 4 wave grid

    // XCD-chunked bijective swizzle (1024 % 8 == 0)
    int bid = blockIdx.x;
    int idx = (bid & 7) * 128 + (bid >> 3);
    int np  = idx & 3;
    int mtb = idx >> 2;          // 0..255
    int b   = mtb >> 3;          // 0..31
    int m0  = (mtb & 7) * 256;
    int n0  = np * 256;

    int srow = lane >> 3;        // 0..7
    int kg   = lane & 7;
    int kgs  = kg ^ srow;        // row&7 == srow for all staged rows
    const _Float16* a16 = v16 + ((size_t)b * S_DIM + m0) * D_DIM;
    const _Float16* bw  = w1t + (size_t)n0 * D_DIM;

    // ---- loop-invariant LDS read bases (halves); kk toggles one XOR bit ----
    int xsw = l15 & 7;
    const _Float16* rA0 = &As[0][0] + (wm * 128 + l15) * 64 + (quad ^ xsw) * 8;
    const _Float16* rA1 = &As[0][0] + (wm * 128 + l15) * 64 + ((4 + quad) ^ xsw) * 8;
    const _Float16* rB0 = &Bs[0][0] + (wn * 64 + l15) * 64 + (quad ^ xsw) * 8;
    const _Float16* rB1 = &Bs[0][0] + (wn * 64 + l15) * 64 + ((4 + quad) ^ xsw) * 8;

    // ---- staging dest bases (wave-uniform + per-issue const offset) ----
    _Float16* dA = &As[0][0] + wid * 512;
    _Float16* dB = &Bs[0][0] + wid * 512;

    // ---- running global source pointers (advanced 64 halves / step) ----
    const _Float16* gA0 = a16 + (size_t)(  0 + wid * 8 + srow) * D_DIM + kgs * 8;
    const _Float16* gA1 = a16 + (size_t)( 64 + wid * 8 + srow) * D_DIM + kgs * 8;
    const _Float16* gA2 = a16 + (size_t)(128 + wid * 8 + srow) * D_DIM + kgs * 8;
    const _Float16* gA3 = a16 + (size_t)(192 + wid * 8 + srow) * D_DIM + kgs * 8;
    const _Float16* gB0 = bw  + (size_t)(  0 + wid * 8 + srow) * D_DIM + kgs * 8;
    const _Float16* gB1 = bw  + (size_t)( 64 + wid * 8 + srow) * D_DIM + kgs * 8;
    const _Float16* gB2 = bw  + (size_t)(128 + wid * 8 + srow) * D_DIM + kgs * 8;
    const _Float16* gB3 = bw  + (size_t)(192 + wid * 8 + srow) * D_DIM + kgs * 8;

    v4f acc[8][4];
    #pragma unroll
    for (int i = 0; i < 8; ++i)
        #pragma unroll
        for (int j = 0; j < 4; ++j) acc[i][j] = (v4f){0.f, 0.f, 0.f, 0.f};

    v8h af_a[4], af_b[4], bf_a[4], bf_b[4];

    // ---- prologue: stage tile 0 into buf0 (pointers advance to koff=64) ----
    STAGE4(gA0, gA1, gA2, gA3, dA, 0)
    STAGE4(gB0, gB1, gB2, gB3, dB, 0)
    asm volatile("s_waitcnt vmcnt(0)" ::: "memory");
    __builtin_amdgcn_s_barrier();
    READ4(af_a, rA0, 0)
    READ4(bf_a, rB0, 0)
    // outstanding: 8 ds_reads (= steady-state entry condition)

    #pragma unroll 1
    for (int tt = 0; tt < 7; ++tt) {
        KSTEP(0, true)
        KSTEP(1, true)
    }
    KSTEP(0, true)
    KSTEP(1, false)

    // ---- epilogue: scores = tanh(acc + qp) . v, reduced over n ----
    float qpv[4], vv[4];
    #pragma unroll
    for (int nt = 0; nt < 4; ++nt) {
        int ng = n0 + wn * 64 + nt * 16 + l15;
        qpv[nt] = qp[b * H_DIM + ng];
        vv[nt]  = v[ng];
    }

    float* s_scores = (float*)&As[0][0];   // all LDS reads done (last barrier)
    if (tid < 256) s_scores[tid] = 0.f;
    __syncthreads();

    #pragma unroll
    for (int mt = 0; mt < 8; ++mt) {
        #pragma unroll
        for (int r = 0; r < 4; ++r) {
            float s = 0.f;
            #pragma unroll
            for (int nt = 0; nt < 4; ++nt) {
                float x = acc[mt][nt][r] + qpv[nt];
                float e = __expf(2.f * x);           // tanh(x) = 1 - 2/(e^{2x}+1)
                s += (1.f - 2.f / (e + 1.f)) * vv[nt];
            }
            s += __shfl_xor(s, 1);
            s += __shfl_xor(s, 2);
            s += __shfl_xor(s, 4);
            s += __shfl_xor(s, 8);
            if (l15 == 0)
                atomicAdd(&s_scores[wm * 128 + mt * 16 + quad * 4 + r], s);
        }
    }
    __syncthreads();
    if (tid < 256) atomicAdd(&scores[(size_t)b * S_DIM + m0 + tid], s_scores[tid]);
}

// ---------------- K2: fused softmax + context ----------------
// One block per batch row b (32 blocks x 1024 thr). Softmax exact (full wout);
// ctx over only weights > 1e-7 (winner-take-all; skipped mass <= 2048e-7 ->
// |ctx err| ~1e-3 << 8.2e-2 threshold). Reads values fp32 directly.
__global__ __launch_bounds__(1024) void k_finish(
        const float* __restrict__ scores, const float* __restrict__ values,
        float* __restrict__ wout, float* __restrict__ ctx) {
    __shared__ float s_w[2048];
    __shared__ int   s_idx[2048];
    __shared__ float red[16];
    __shared__ float s_bcast;
    __shared__ int   s_cnt;

    int b = blockIdx.x, tid = threadIdx.x;
    int lane = tid & 63, wid = tid >> 6;

    float s0 = scores[b * S_DIM + tid];
    float s1 = scores[b * S_DIM + 1024 + tid];

    float m = fmaxf(s0, s1);
    #pragma unroll
    for (int off = 1; off <= 32; off <<= 1) m = fmaxf(m, __shfl_xor(m, off));
    if (lane == 0) red[wid] = m;
    if (tid == 0) s_cnt = 0;
    __syncthreads();
    if (tid == 0) {
        float mm = red[0];
        #pragma unroll
        for (int i = 1; i < 16; ++i) mm = fmaxf(mm, red[i]);
        s_bcast = mm;
    }
    __syncthreads();
    float rowmax = s_bcast;

    float e0 = __expf(s0 - rowmax);
    float e1 = __expf(s1 - rowmax);
    float sum = e0 + e1;
    #pragma unroll
    for (int off = 1; off <= 32; off <<= 1) sum += __shfl_xor(sum, off);
    if (lane == 0) red[wid] = sum;
    __syncthreads();
    if (tid == 0) {
        float ss = red[0];
        #pragma unroll
        for (int i = 1; i < 16; ++i) ss += red[i];
        s_bcast = 1.f / ss;
    }
    __syncthreads();
    float inv = s_bcast;

    float w0 = e0 * inv, w1 = e1 * inv;
    wout[b * S_DIM + tid]        = w0;
    wout[b * S_DIM + 1024 + tid] = w1;
    s_w[tid]        = w0;
    s_w[tid + 1024] = w1;

    if (w0 > 1e-7f) { int p = atomicAdd(&s_cnt, 1); s_idx[p] = tid; }
    if (w1 > 1e-7f) { int p = atomicAdd(&s_cnt, 1); s_idx[p] = tid + 1024; }
    __syncthreads();
    int cnt = s_cnt;

    float acc = 0.f;
    const float* vb = values + (size_t)b * S_DIM * D_DIM + tid;
    for (int i = 0; i < cnt; ++i) {
        int s = s_idx[i];
        acc += s_w[s] * vb[(size_t)s * D_DIM];
    }
    ctx[b * D_DIM + tid] = acc;
}

extern "C" void kernel_launch(void* const* d_in, const int* in_sizes, int n_in,
                              void* d_out, int out_size, void* d_ws, size_t ws_size,
                              hipStream_t stream) {
    const float* query  = (const float*)d_in[0];
    const float* values = (const float*)d_in[1];
    const float* W1     = (const float*)d_in[2];
    const float* W2     = (const float*)d_in[3];
    const float* v      = (const float*)d_in[4];

    char* ws = (char*)d_ws;
    _Float16* v16 = (_Float16*)(ws + WS_V16);
    _Float16* w1t = (_Float16*)(ws + WS_W1T);
    float* qp     = (float*)(ws + WS_QP);
    float* scores = (float*)(ws + WS_SCORES);

    float* ctx  = (float*)d_out;            // [32, 1024]
    float* wout = (float*)d_out + 32768;    // [32, 2048]

    k_prep<<<dim3(33312), 256, 0, stream>>>(values, v16, W1, w1t, query, W2, qp, scores);
    k_scores<<<dim3(1024), 512, 0, stream>>>(v16, w1t, qp, v, scores);
    k_finish<<<dim3(32), 1024, 0, stream>>>(scores, values, wout, ctx);
}